// Round 1
// baseline (169.419 us; speedup 1.0000x reference)
//
#include <hip/hip_runtime.h>

// B3-spline UWT, 3 levels, fp32, x: (16,1024,1024) -> out: (16,4,1024,1024)
// out[:,0..2] = wavelet coeffs w1..w3, out[:,3] = residual c3.

#define B3_W0 0.0625f   // 1/16
#define B3_W1 0.25f     // 1/4
#define B3_W2 0.375f    // 3/8

constexpr int TB = 256;   // threads per block
constexpr int TY = 32;    // output tile rows (H)
constexpr int TX = 64;    // output tile cols (W), contiguous

// One wavelet level: y = B3smooth_d(src) (separable, reflect pad), then
//   cdst = y;  wdst = src - y (if wdst != nullptr).
// Batch strides are in elements (output tensor has batch stride 4*H*W).
template<int D>
__global__ __launch_bounds__(TB)
void uwt_level_kernel(const float* __restrict__ src, long src_bs,
                      float* __restrict__ wdst, long w_bs,
                      float* __restrict__ cdst, long c_bs,
                      int H, int W)
{
    constexpr int HR = 2 * D;          // halo radius
    constexpr int RW = TX + 4 * D;     // tile row width (with halo)
    constexpr int RH = TY + 4 * D;     // tile rows (with halo)

    __shared__ float tile[RH * RW];
    __shared__ float htmp[TY * RW];

    const int bx = blockIdx.x * TX;
    const int by = blockIdx.y * TY;
    const int b  = blockIdx.z;

    const float* sp = src + (long)b * src_bs;
    const int tid = threadIdx.x;

    // ---- load input tile with reflect boundary ----
    for (int e = tid; e < RH * RW; e += TB) {
        int r = e / RW, c = e % RW;
        int gh = by + r - HR;
        int gw = bx + c - HR;
        gh = (gh < 0) ? -gh : ((gh >= H) ? (2 * H - 2 - gh) : gh);
        gw = (gw < 0) ? -gw : ((gw >= W) ? (2 * W - 2 - gw) : gw);
        tile[e] = sp[(long)gh * W + gw];
    }
    __syncthreads();

    // ---- conv along H (rows) into htmp ----
    for (int e = tid; e < TY * RW; e += TB) {
        int r = e / RW, c = e % RW;
        const float* t0 = &tile[r * RW + c];
        float v = B3_W0 * (t0[0]          + t0[4 * D * RW])
                + B3_W1 * (t0[D * RW]     + t0[3 * D * RW])
                + B3_W2 *  t0[2 * D * RW];
        htmp[e] = v;
    }
    __syncthreads();

    // ---- conv along W (cols), write outputs ----
    float* wp = wdst ? (wdst + (long)b * w_bs) : nullptr;
    float* cp = cdst + (long)b * c_bs;
    for (int e = tid; e < TY * TX; e += TB) {
        int r = e / TX, c = e % TX;
        const float* h0 = &htmp[r * RW + c];
        float v = B3_W0 * (h0[0]     + h0[4 * D])
                + B3_W1 * (h0[D]     + h0[3 * D])
                + B3_W2 *  h0[2 * D];
        long gi = (long)(by + r) * W + (bx + c);
        cp[gi] = v;
        if (wp) wp[gi] = tile[(r + 2 * D) * RW + (c + 2 * D)] - v;
    }
}

// out_a[b*stride + i] -= out_b[b*stride + i]  over (B, plane) elems, float4.
__global__ __launch_bounds__(TB)
void sub_inplace_kernel(float* __restrict__ a, const float* __restrict__ s,
                        long bstride, long plane, int B)
{
    long total4 = (long)B * (plane / 4);
    long p4 = plane / 4;
    for (long i = (long)blockIdx.x * blockDim.x + threadIdx.x;
         i < total4;
         i += (long)gridDim.x * blockDim.x) {
        long b = i / p4;
        long e = i - b * p4;
        float4* ap = (float4*)(a + b * bstride) + e;
        const float4* sp = (const float4*)(s + b * bstride) + e;
        float4 av = *ap, sv = *sp;
        av.x -= sv.x; av.y -= sv.y; av.z -= sv.z; av.w -= sv.w;
        *ap = av;
    }
}

static inline void launch_level(int d,
                                const float* src, long src_bs,
                                float* wdst, long w_bs,
                                float* cdst, long c_bs,
                                int B, int H, int W, hipStream_t stream)
{
    dim3 grid(W / TX, H / TY, B);
    dim3 block(TB);
    switch (d) {
    case 1: uwt_level_kernel<1><<<grid, block, 0, stream>>>(src, src_bs, wdst, w_bs, cdst, c_bs, H, W); break;
    case 2: uwt_level_kernel<2><<<grid, block, 0, stream>>>(src, src_bs, wdst, w_bs, cdst, c_bs, H, W); break;
    case 4: uwt_level_kernel<4><<<grid, block, 0, stream>>>(src, src_bs, wdst, w_bs, cdst, c_bs, H, W); break;
    }
}

extern "C" void kernel_launch(void* const* d_in, const int* in_sizes, int n_in,
                              void* d_out, int out_size, void* d_ws, size_t ws_size,
                              hipStream_t stream)
{
    const int B = 16, H = 1024, W = 1024;
    const long plane = (long)H * W;          // 1M elems
    const long out_bs = 4 * plane;           // out batch stride

    const float* x = (const float*)d_in[0];
    float* out = (float*)d_out;

    float* o0 = out + 0 * plane;  // w1
    float* o1 = out + 1 * plane;  // w2
    float* o2 = out + 2 * plane;  // w3
    float* o3 = out + 3 * plane;  // c3

    if (ws_size >= (size_t)2 * plane * B * sizeof(float)) {
        // ws double-buffer path
        float* wsA = (float*)d_ws;
        float* wsB = wsA + (long)B * plane;
        // L1: src=x -> w1, c1(wsA)
        launch_level(1, x, plane, o0, out_bs, wsA, plane, B, H, W, stream);
        // L2: src=c1 -> w2, c2(wsB)
        launch_level(2, wsA, plane, o1, out_bs, wsB, plane, B, H, W, stream);
        // L3: src=c2 -> w3, c3
        launch_level(4, wsB, plane, o2, out_bs, o3, out_bs, B, H, W, stream);
    } else {
        // route intermediates through output channels
        // L1: src=x -> w1 (o0), c1 (o3 temp)
        launch_level(1, x, plane, o0, out_bs, o3, out_bs, B, H, W, stream);
        // L2: src=c1(o3) -> w2 (o1), c2 (o2 temp)
        launch_level(2, o3, out_bs, o1, out_bs, o2, out_bs, B, H, W, stream);
        // L3a: src=c2(o2) -> smooth only -> c3 (o3)
        launch_level(4, o2, out_bs, nullptr, 0, o3, out_bs, B, H, W, stream);
        // L3b: w3 = c2 - c3  (o2 -= o3), elementwise
        sub_inplace_kernel<<<2048, TB, 0, stream>>>(o2, o3, out_bs, plane, B);
    }
}

// Round 2
// 106.473 us; speedup vs baseline: 1.5912x; 1.5912x over previous
//
#include <hip/hip_runtime.h>

// Fused 3-level B3-spline UWT, fp32.
// x: (16,1024,1024) -> out: (16,4,1024,1024) = [w1,w2,w3,c3].
// One kernel: each block produces a 64x64 output tile of all 4 planes from a
// 96x96 input tile (halo 16 >= 2+4+8=14, rounded up for float4 alignment).
// Two LDS ping-pong buffers; per level: H-conv (register-blocked, float4)
// then W-conv (aligned-span float4 reads). Centers of x/c1/c2 stashed in
// registers to form w_i = prev - smooth without extra LDS passes.

constexpr float B3W0 = 0.0625f, B3W1 = 0.25f, B3W2 = 0.375f;
constexpr int TB   = 512;
constexpr int TILE = 64;
constexpr int HALO = 16;
constexpr int IN   = 96;          // TILE + 2*HALO
constexpr int CW4  = IN / 4;      // 24 float4 per row
constexpr int SLACK = 16;         // front/back float slack for off-edge f4 reads
constexpr int BUF4  = (SLACK + IN * IN + SLACK) / 4;  // 2312 float4
constexpr int HW = 1024 * 1024;

__device__ __forceinline__ float4 ld4(const float* p, int r, int c) {
    return *(const float4*)(p + r * IN + c);
}
__device__ __forceinline__ void st4(float* p, int r, int c, float4 v) {
    *(float4*)(p + r * IN + c) = v;
}

// H-conv (along rows axis), dilation D, R-row register blocking.
// Writes dst rows [row0, row0 + nrb*R), all 24 col-groups.
template<int D, int R>
__device__ __forceinline__ void hconv(const float* __restrict__ src,
                                      float* __restrict__ dst,
                                      int row0, int nrb, int tid) {
    const int NIT = nrb * CW4;
    for (int it = tid; it < NIT; it += TB) {
        const int rb = it / CW4;
        const int c  = (it - rb * CW4) * 4;
        const int r0 = row0 + rb * R;
        float4 acc[R];
#pragma unroll
        for (int j = 0; j < R; ++j) acc[j] = float4{0.f, 0.f, 0.f, 0.f};
#pragma unroll
        for (int i = 0; i < R + 4 * D; ++i) {          // stream input rows
            const float4 v = ld4(src, r0 - 2 * D + i, c);
#pragma unroll
            for (int k = 0; k < 5; ++k) {
                const int j = i - k * D;               // compile-time per (i,k)
                if (j >= 0 && j < R) {
                    const float w = (k == 2) ? B3W2 : ((k == 1 || k == 3) ? B3W1 : B3W0);
                    acc[j].x += w * v.x; acc[j].y += w * v.y;
                    acc[j].z += w * v.z; acc[j].w += w * v.w;
                }
            }
        }
#pragma unroll
        for (int j = 0; j < R; ++j) st4(dst, r0 + j, c, acc[j]);
    }
}

// W-conv (along cols axis), dilation D. Aligned float4 span reads.
// Writes dst rows [rA, rA+nrows), all 24 col-groups.
template<int D>
__device__ __forceinline__ void wconv(const float* __restrict__ src,
                                      float* __restrict__ dst,
                                      int rA, int nrows, int tid) {
    constexpr int AOFF = (D == 4) ? 8 : 4;   // floats of left extension (aligned)
    constexpr int NR   = (D == 4) ? 5 : 3;   // float4 reads per output float4
    const int NIT = nrows * CW4;
    for (int it = tid; it < NIT; it += TB) {
        const int rr = it / CW4;
        const int c0 = (it - rr * CW4) * 4;
        const int r  = rA + rr;
        float F[NR * 4];
#pragma unroll
        for (int m = 0; m < NR; ++m)
            *(float4*)&F[4 * m] = ld4(src, r, c0 - AOFF + 4 * m);
        float4 o;
#pragma unroll
        for (int i = 0; i < 4; ++i) {
            (&o.x)[i] = B3W0 * (F[i + AOFF - 2 * D] + F[i + AOFF + 2 * D])
                      + B3W1 * (F[i + AOFF - D]     + F[i + AOFF + D])
                      + B3W2 *  F[i + AOFF];
        }
        st4(dst, r, c0, o);
    }
}

__device__ __forceinline__ float4 sub4(float4 a, float4 b) {
    return float4{a.x - b.x, a.y - b.y, a.z - b.z, a.w - b.w};
}

__global__ __launch_bounds__(TB, 2)
void uwt_fused_kernel(const float* __restrict__ x, float* __restrict__ out)
{
    __shared__ float4 rawA[BUF4], rawB[BUF4];
    float* A = (float*)rawA + SLACK;
    float* B = (float*)rawB + SLACK;

    const int tid = threadIdx.x;
    const int bx = blockIdx.x * TILE;
    const int by = blockIdx.y * TILE;
    const float* xp = x + (size_t)blockIdx.z * HW;
    float* op = out + (size_t)blockIdx.z * 4 * HW;

    // ---- load x tile [0,96)x[0,96) into A (reflect boundary) ----
    if (bx != 0 && bx != 1024 - TILE) {
        // interior in W: float4 loads, row reflect only
        for (int e = tid; e < IN * CW4; e += TB) {
            const int r = e / CW4, m = e - r * CW4;
            int gr = by - HALO + r;
            gr = gr < 0 ? -gr : (gr >= 1024 ? 2046 - gr : gr);
            const float4 v = *(const float4*)(xp + (size_t)gr * 1024 + (bx - HALO + 4 * m));
            st4(A, r, 4 * m, v);
        }
    } else {
        for (int e = tid; e < IN * IN; e += TB) {
            const int r = e / IN, cc = e - r * IN;
            int gr = by - HALO + r;
            gr = gr < 0 ? -gr : (gr >= 1024 ? 2046 - gr : gr);
            int gc = bx - HALO + cc;
            gc = gc < 0 ? -gc : (gc >= 1024 ? 2046 - gc : gc);
            A[r * IN + cc] = xp[(size_t)gr * 1024 + gc];
        }
    }
    __syncthreads();

    // ---- stash x center (2 float4/thread) ; h1 = Hconv_d1(x): A->B rows [4,92) ----
    float4 stx[2], st1[2], st2[2];
#pragma unroll
    for (int q = 0; q < 2; ++q) {
        const int it = tid + q * TB;
        const int r = it >> 4, g = it & 15;
        stx[q] = ld4(A, HALO + r, HALO + 4 * g);
    }
    hconv<1, 4>(A, B, 4, 22, tid);
    __syncthreads();

    // ---- c1 = Wconv_d1(h1): B->A rows [4,92) ----
    wconv<1>(B, A, 4, 88, tid);
    __syncthreads();

    // ---- w1 = x - c1 (center), stash c1 ; h2 = Hconv_d2(c1): A->B rows [8,88) ----
#pragma unroll
    for (int q = 0; q < 2; ++q) {
        const int it = tid + q * TB;
        const int r = it >> 4, g = it & 15;
        const float4 c = ld4(A, HALO + r, HALO + 4 * g);
        st1[q] = c;
        *(float4*)(op + 0 * HW + (size_t)(by + r) * 1024 + bx + 4 * g) = sub4(stx[q], c);
    }
    hconv<2, 4>(A, B, 8, 20, tid);
    __syncthreads();

    // ---- c2 = Wconv_d2(h2): B->A rows [8,88) ----
    wconv<2>(B, A, 8, 80, tid);
    __syncthreads();

    // ---- w2 = c1 - c2 (center), stash c2 ; h3 = Hconv_d4(c2): A->B rows [16,80) ----
#pragma unroll
    for (int q = 0; q < 2; ++q) {
        const int it = tid + q * TB;
        const int r = it >> 4, g = it & 15;
        const float4 c = ld4(A, HALO + r, HALO + 4 * g);
        st2[q] = c;
        *(float4*)(op + 1 * HW + (size_t)(by + r) * 1024 + bx + 4 * g) = sub4(st1[q], c);
    }
    hconv<4, 4>(A, B, 16, 16, tid);
    __syncthreads();

    // ---- y3 = Wconv_d4(h3) on center only (in regs); w3 = c2 - y3; c3 = y3 ----
#pragma unroll
    for (int q = 0; q < 2; ++q) {
        const int it = tid + q * TB;
        const int r = it >> 4, g = it & 15;
        const int rr = HALO + r, c0 = HALO + 4 * g;
        float F[20];
#pragma unroll
        for (int m = 0; m < 5; ++m)
            *(float4*)&F[4 * m] = ld4(B, rr, c0 - 8 + 4 * m);
        float4 y;
#pragma unroll
        for (int i = 0; i < 4; ++i)
            (&y.x)[i] = B3W0 * (F[i] + F[i + 16]) + B3W1 * (F[i + 4] + F[i + 12])
                      + B3W2 * F[i + 8];
        *(float4*)(op + 2 * HW + (size_t)(by + r) * 1024 + bx + 4 * g) = sub4(st2[q], y);
        *(float4*)(op + 3 * HW + (size_t)(by + r) * 1024 + bx + 4 * g) = y;
    }
}

extern "C" void kernel_launch(void* const* d_in, const int* in_sizes, int n_in,
                              void* d_out, int out_size, void* d_ws, size_t ws_size,
                              hipStream_t stream)
{
    const float* x = (const float*)d_in[0];
    float* out = (float*)d_out;
    dim3 grid(1024 / TILE, 1024 / TILE, 16);
    uwt_fused_kernel<<<grid, dim3(TB), 0, stream>>>(x, out);
}

// Round 3
// 101.901 us; speedup vs baseline: 1.6626x; 1.0449x over previous
//
#include <hip/hip_runtime.h>

// Fused 3-level B3-spline UWT via composed dense kernels, fp32.
// x: (16,1024,1024) -> out: (16,4,1024,1024) = [w1,w2,w3,c3].
// c_i = V_i U_i x, where U/V are the composed horizontal/vertical kernels:
//   level1: 5-tap  [1,4,6,4,1]/16
//   level2: 13-tap [1,4,10,20,31,40,44,40,31,20,10,4,1]/256      (B3_d2 * B3_d1)
//   level3: 29-tap [1,4,10,20,35,56,84,120,161,204,246,284,315,336,344,...]/4096
// One block: 128x64 output tile, 156x96 input tile, 2 barriers.

typedef float f4v __attribute__((ext_vector_type(4)));

constexpr int TB   = 512;
constexpr int TROW = 128;
constexpr int TCOL = 64;
constexpr int VH   = 14;           // total halo radius (2+4+8)
constexpr int XR   = TROW + 28;    // 156 x-tile rows
constexpr int XP   = 100;          // x-tile pitch (96 cols + pad, ≡4 mod 32 banks)
constexpr int U2R  = TROW + 12;    // 140 u2 rows
constexpr int U3R  = TROW + 28;    // 156 u3 rows
constexpr int UP   = 68;           // u-tile pitch (64 + pad)
constexpr int HW   = 1024 * 1024;

__device__ constexpr float K5[5] = {0.0625f, 0.25f, 0.375f, 0.25f, 0.0625f};
__device__ constexpr float K13[13] = {
    1.f/256, 4.f/256, 10.f/256, 20.f/256, 31.f/256, 40.f/256, 44.f/256,
    40.f/256, 31.f/256, 20.f/256, 10.f/256, 4.f/256, 1.f/256};
__device__ constexpr float K29[29] = {
    1.f/4096,   4.f/4096,  10.f/4096,  20.f/4096,  35.f/4096,  56.f/4096,
    84.f/4096, 120.f/4096, 161.f/4096, 204.f/4096, 246.f/4096, 284.f/4096,
    315.f/4096, 336.f/4096, 344.f/4096, 336.f/4096, 315.f/4096, 284.f/4096,
    246.f/4096, 204.f/4096, 161.f/4096, 120.f/4096,  84.f/4096,  56.f/4096,
    35.f/4096,  20.f/4096,  10.f/4096,   4.f/4096,   1.f/4096};

__device__ __forceinline__ int refl(int i) {
    return i < 0 ? -i : (i >= 1024 ? 2046 - i : i);
}

// u-tile index with per-4-row bank shift: strips 4 rows apart land on
// different bank quartets (keeps passB strip reads 2-way = free).
__device__ __forceinline__ int uidx(int row, int fc) {
    return row * UP + ((4 * fc + ((row & 12) << 1)) & 63);
}

__global__ __launch_bounds__(TB)
void uwt3_kernel(const float* __restrict__ x, float* __restrict__ out)
{
    __shared__ float xs[XR * XP];     // 62.4 KB
    __shared__ float u2s[U2R * UP];   // 38.1 KB
    __shared__ float u3s[U3R * UP];   // 42.4 KB

    const int tid = threadIdx.x;
    const int bx = blockIdx.x * TCOL;
    const int by = blockIdx.y * TROW;
    const float* xp = x + (size_t)blockIdx.z * HW;
    float* op = out + (size_t)blockIdx.z * 4 * HW;

    // ---- load x tile: rows [by-14, by+142), cols [bx-16, bx+80) ----
    if (blockIdx.x != 0 && blockIdx.x != 15) {
        for (int e = tid; e < XR * 24; e += TB) {
            const int r = e / 24, m = e - r * 24;
            const int gr = refl(by - VH + r);
            const f4v v = *(const f4v*)(xp + (size_t)gr * 1024 + (bx - 16 + 4 * m));
            *(f4v*)(xs + r * XP + 4 * m) = v;
        }
    } else {
        for (int e = tid; e < XR * 96; e += TB) {
            const int r = e / 96, c = e - r * 96;
            const int gr = refl(by - VH + r);
            const int gc = refl(bx - 16 + c);
            xs[r * XP + c] = xp[(size_t)gr * 1024 + gc];
        }
    }
    __syncthreads();

    // ---- passA: horizontal composed convs -> u2 (13 taps), u3 (29 taps) ----
    {
        const int gi = tid >> 7;          // 16-float group 0..3
        const int rbase = tid & 127;
        for (int rr = rbase; rr < XR; rr += 128) {
            float F[48];
            const float* base = xs + rr * XP + 16 * gi;
#pragma unroll
            for (int m = 0; m < 12; ++m)
                *(f4v*)&F[4 * m] = *(const f4v*)(base + 4 * m);
            // centers: float col 16*gi + cc  <->  F[16 + cc], cc in [0,16)
#pragma unroll
            for (int k = 0; k < 4; ++k) {
                f4v a = {0.f, 0.f, 0.f, 0.f};
#pragma unroll
                for (int t = 0; t < 29; ++t) {
#pragma unroll
                    for (int q = 0; q < 4; ++q)
                        a[q] += K29[t] * F[2 + 4 * k + q + t];
                }
                *(f4v*)(u3s + uidx(rr, 4 * gi + k)) = a;
            }
            if (rr >= 8 && rr < 8 + U2R) {
#pragma unroll
                for (int k = 0; k < 4; ++k) {
                    f4v a = {0.f, 0.f, 0.f, 0.f};
#pragma unroll
                    for (int t = 0; t < 13; ++t) {
#pragma unroll
                        for (int q = 0; q < 4; ++q)
                            a[q] += K13[t] * F[10 + 4 * k + q + t];
                    }
                    *(f4v*)(u2s + uidx(rr - 8, 4 * gi + k)) = a;
                }
            }
        }
    }
    __syncthreads();

    // ---- passB: vertical convs + outputs. thread = (f4-col, 4-row strip) ----
    const int fc = tid & 15;
    const int s  = tid >> 4;
    const int r0 = s * 4;
    const size_t gbase = (size_t)(by + r0) * 1024 + bx + 4 * fc;

    // c1 = V1(U1 x) from x tile directly; also capture x center for w1
    f4v c1[4], xc[4];
    {
        f4v u1r[8];
#pragma unroll
        for (int i = 0; i < 8; ++i) {
            const float* base = xs + (r0 + 12 + i) * XP + 12 + 4 * fc;
            float f[12];
#pragma unroll
            for (int m = 0; m < 3; ++m)
                *(f4v*)&f[4 * m] = *(const f4v*)(base + 4 * m);
            if (i >= 2 && i < 6) xc[i - 2] = *(const f4v*)&f[4];
            f4v a = {0.f, 0.f, 0.f, 0.f};
#pragma unroll
            for (int t = 0; t < 5; ++t) {
#pragma unroll
                for (int q = 0; q < 4; ++q)
                    a[q] += K5[t] * f[2 + q + t];
            }
            u1r[i] = a;
        }
#pragma unroll
        for (int j = 0; j < 4; ++j) {
            f4v a = {0.f, 0.f, 0.f, 0.f};
#pragma unroll
            for (int t = 0; t < 5; ++t)
                a += K5[t] * u1r[j + t];
            c1[j] = a;
        }
    }
#pragma unroll
    for (int j = 0; j < 4; ++j) {
        const f4v w = xc[j] - c1[j];
        __builtin_nontemporal_store(w, (f4v*)(op + 0 * HW + gbase + (size_t)j * 1024));
    }

    // c2 = V2 u2 (13 taps dense)
    f4v c2[4] = {{0.f,0.f,0.f,0.f},{0.f,0.f,0.f,0.f},{0.f,0.f,0.f,0.f},{0.f,0.f,0.f,0.f}};
#pragma unroll
    for (int i = 0; i < 16; ++i) {
        const f4v v = *(const f4v*)(u2s + uidx(r0 + i, fc));
#pragma unroll
        for (int j = 0; j < 4; ++j) {
            const int m = i - j;
            if (m >= 0 && m <= 12) c2[j] += K13[m] * v;
        }
    }
#pragma unroll
    for (int j = 0; j < 4; ++j) {
        const f4v w = c1[j] - c2[j];
        __builtin_nontemporal_store(w, (f4v*)(op + 1 * HW + gbase + (size_t)j * 1024));
    }

    // c3 = V3 u3 (29 taps dense)
    f4v c3[4] = {{0.f,0.f,0.f,0.f},{0.f,0.f,0.f,0.f},{0.f,0.f,0.f,0.f},{0.f,0.f,0.f,0.f}};
#pragma unroll
    for (int i = 0; i < 32; ++i) {
        const f4v v = *(const f4v*)(u3s + uidx(r0 + i, fc));
#pragma unroll
        for (int j = 0; j < 4; ++j) {
            const int m = i - j;
            if (m >= 0 && m <= 28) c3[j] += K29[m] * v;
        }
    }
#pragma unroll
    for (int j = 0; j < 4; ++j) {
        const f4v w = c2[j] - c3[j];
        __builtin_nontemporal_store(w, (f4v*)(op + 2 * HW + gbase + (size_t)j * 1024));
        __builtin_nontemporal_store(c3[j], (f4v*)(op + 3 * HW + gbase + (size_t)j * 1024));
    }
}

extern "C" void kernel_launch(void* const* d_in, const int* in_sizes, int n_in,
                              void* d_out, int out_size, void* d_ws, size_t ws_size,
                              hipStream_t stream)
{
    const float* x = (const float*)d_in[0];
    float* out = (float*)d_out;
    dim3 grid(1024 / TCOL, 1024 / TROW, 16);   // (16, 8, 16)
    uwt3_kernel<<<grid, dim3(TB), 0, stream>>>(x, out);
}

// Round 4
// 89.264 us; speedup vs baseline: 1.8979x; 1.1416x over previous
//
#include <hip/hip_runtime.h>

// Fused 3-level B3-spline UWT via composed dense kernels, fp32.
// x: (16,1024,1024) -> out: (16,4,1024,1024) = [w1,w2,w3,c3].
// c_i = V_i U_i x with composed taps:
//   L1: 5-tap [1,4,6,4,1]/16
//   L2: 13-tap (B3_d2 * B3_d1) /256
//   L3: 29-tap (B3_d4 * B3_d2 * B3_d1) /4096
// 64x64 output tile, 92x96 input tile, 2 barriers, 79.8 KB LDS -> 2 blocks/CU.

typedef float f4v __attribute__((ext_vector_type(4)));

constexpr int TB   = 512;
constexpr int TROW = 64;
constexpr int TCOL = 64;
constexpr int VH   = 14;          // vertical halo (2+4+8)
constexpr int XR   = TROW + 28;   // 92 x-tile rows
constexpr int XP   = 100;         // x-tile pitch (96 cols + 4; 100 % 32 == 4)
constexpr int U2R  = TROW + 12;   // 76
constexpr int U3R  = TROW + 28;   // 92
constexpr int UP   = 64;          // u-tile pitch (bank safety via XOR swizzle)
constexpr int HW   = 1024 * 1024;

__device__ constexpr float K5[5] = {0.0625f, 0.25f, 0.375f, 0.25f, 0.0625f};
__device__ constexpr float K13[13] = {
    1.f/256, 4.f/256, 10.f/256, 20.f/256, 31.f/256, 40.f/256, 44.f/256,
    40.f/256, 31.f/256, 20.f/256, 10.f/256, 4.f/256, 1.f/256};
__device__ constexpr float K29[29] = {
    1.f/4096,   4.f/4096,  10.f/4096,  20.f/4096,  35.f/4096,  56.f/4096,
    84.f/4096, 120.f/4096, 161.f/4096, 204.f/4096, 246.f/4096, 284.f/4096,
    315.f/4096, 336.f/4096, 344.f/4096, 336.f/4096, 315.f/4096, 284.f/4096,
    246.f/4096, 204.f/4096, 161.f/4096, 120.f/4096,  84.f/4096,  56.f/4096,
    35.f/4096,  20.f/4096,  10.f/4096,   4.f/4096,   1.f/4096};

__device__ __forceinline__ int refl(int i) {
    return i < 0 ? -i : (i >= 1024 ? 2046 - i : i);
}

// u-tile addressing: f4-quartet XOR swizzle. Spreads any {rows spaced 1 or 2,
// cols across lanes} wave access over all 8 bank-quartets (b128 minimum).
__device__ __forceinline__ int uidx(int row, int q) {
    return row * UP + 4 * (q ^ (row & 7));
}

__global__ __launch_bounds__(TB, 4)
void uwt3_kernel(const float* __restrict__ x, float* __restrict__ out)
{
    __shared__ float xs[XR * XP];     // 36.8 KB
    __shared__ float u2s[U2R * UP];   // 19.0 KB
    __shared__ float u3s[U3R * UP];   // 23.0 KB

    const int tid = threadIdx.x;

    // bijective XCD chunk swizzle: XCD k handles contiguous work [512k,512k+512)
    const int flat = blockIdx.x;                  // 0..4095
    const int swz  = (flat & 7) * 512 + (flat >> 3);
    const int bxi = swz & 15;
    const int byi = (swz >> 4) & 15;
    const int bz  = swz >> 8;
    const int bx = bxi * TCOL;
    const int by = byi * TROW;

    const float* xp = x + (size_t)bz * HW;
    float* op = out + (size_t)bz * 4 * HW;

    // ---- load x tile: rows [by-14, by+78), cols [bx-16, bx+80) ----
    if (bxi != 0 && bxi != 15) {
        for (int e = tid; e < XR * 24; e += TB) {
            const int r = e / 24, m = e - r * 24;
            const int gr = refl(by - VH + r);
            const f4v v = *(const f4v*)(xp + (size_t)gr * 1024 + (bx - 16 + 4 * m));
            *(f4v*)(xs + r * XP + 4 * m) = v;
        }
    } else {
        for (int e = tid; e < XR * 96; e += TB) {
            const int r = e / 96, c = e - r * 96;
            const int gr = refl(by - VH + r);
            const int gc = refl(bx - 16 + c);
            xs[r * XP + c] = xp[(size_t)gr * 1024 + gc];
        }
    }
    __syncthreads();

    // ---- passA: horizontal composed convs -> u2 (13-tap), u3 (29-tap) ----
    {
        const int gi = tid & 3;        // 16-float output group
        const int rp = tid >> 2;       // xs row
        if (rp < XR) {
            float F[48];
            const float* base = xs + rp * XP + 16 * gi;
#pragma unroll
            for (int m = 0; m < 12; ++m)
                *(f4v*)&F[4 * m] = *(const f4v*)(base + 4 * m);
#pragma unroll
            for (int k = 0; k < 4; ++k) {
                f4v a = {0.f, 0.f, 0.f, 0.f};
#pragma unroll
                for (int t = 0; t < 29; ++t) {
#pragma unroll
                    for (int q = 0; q < 4; ++q)
                        a[q] += K29[t] * F[2 + 4 * k + q + t];
                }
                *(f4v*)(u3s + uidx(rp, 4 * gi + k)) = a;
            }
            if (rp >= 8 && rp < 8 + U2R) {
#pragma unroll
                for (int k = 0; k < 4; ++k) {
                    f4v a = {0.f, 0.f, 0.f, 0.f};
#pragma unroll
                    for (int t = 0; t < 13; ++t) {
#pragma unroll
                        for (int q = 0; q < 4; ++q)
                            a[q] += K13[t] * F[10 + 4 * k + q + t];
                    }
                    *(f4v*)(u2s + uidx(rp - 8, 4 * gi + k)) = a;
                }
            }
        }
    }
    __syncthreads();

    // ---- passB: vertical convs + all 4 outputs. thread = (f4-col, 2-row strip) ----
    const int fc = tid & 15;
    const int r0 = (tid >> 4) * 2;
    const size_t gbase = (size_t)(by + r0) * 1024 + bx + 4 * fc;

    // c1 = V1(U1 x) directly from x tile; capture x center for w1
    f4v c1[2], xc[2];
    {
        f4v u1r[6];
#pragma unroll
        for (int i = 0; i < 6; ++i) {
            const float* base = xs + (r0 + 12 + i) * XP + 12 + 4 * fc;
            float f[12];
#pragma unroll
            for (int m = 0; m < 3; ++m)
                *(f4v*)&f[4 * m] = *(const f4v*)(base + 4 * m);
            if (i == 2) xc[0] = *(const f4v*)&f[4];
            if (i == 3) xc[1] = *(const f4v*)&f[4];
            f4v a = {0.f, 0.f, 0.f, 0.f};
#pragma unroll
            for (int t = 0; t < 5; ++t) {
#pragma unroll
                for (int q = 0; q < 4; ++q)
                    a[q] += K5[t] * f[2 + q + t];
            }
            u1r[i] = a;
        }
#pragma unroll
        for (int j = 0; j < 2; ++j) {
            f4v a = {0.f, 0.f, 0.f, 0.f};
#pragma unroll
            for (int t = 0; t < 5; ++t)
                a += K5[t] * u1r[j + t];
            c1[j] = a;
        }
    }
#pragma unroll
    for (int j = 0; j < 2; ++j)
        __builtin_nontemporal_store(xc[j] - c1[j],
            (f4v*)(op + 0 * HW + gbase + (size_t)j * 1024));

    // c2 = V2 u2 (13-tap dense)
    f4v c2[2] = {{0.f,0.f,0.f,0.f},{0.f,0.f,0.f,0.f}};
#pragma unroll
    for (int i = 0; i < 14; ++i) {
        const f4v v = *(const f4v*)(u2s + uidx(r0 + i, fc));
        if (i <= 12) c2[0] += K13[i] * v;
        if (i >= 1)  c2[1] += K13[i - 1] * v;
    }
#pragma unroll
    for (int j = 0; j < 2; ++j)
        __builtin_nontemporal_store(c1[j] - c2[j],
            (f4v*)(op + 1 * HW + gbase + (size_t)j * 1024));

    // c3 = V3 u3 (29-tap dense)
    f4v c3[2] = {{0.f,0.f,0.f,0.f},{0.f,0.f,0.f,0.f}};
#pragma unroll
    for (int i = 0; i < 30; ++i) {
        const f4v v = *(const f4v*)(u3s + uidx(r0 + i, fc));
        if (i <= 28) c3[0] += K29[i] * v;
        if (i >= 1)  c3[1] += K29[i - 1] * v;
    }
#pragma unroll
    for (int j = 0; j < 2; ++j) {
        __builtin_nontemporal_store(c2[j] - c3[j],
            (f4v*)(op + 2 * HW + gbase + (size_t)j * 1024));
        __builtin_nontemporal_store(c3[j],
            (f4v*)(op + 3 * HW + gbase + (size_t)j * 1024));
    }
}

extern "C" void kernel_launch(void* const* d_in, const int* in_sizes, int n_in,
                              void* d_out, int out_size, void* d_ws, size_t ws_size,
                              hipStream_t stream)
{
    const float* x = (const float*)d_in[0];
    float* out = (float*)d_out;
    uwt3_kernel<<<dim3(4096), dim3(TB), 0, stream>>>(x, out);
}

// Round 5
// 87.514 us; speedup vs baseline: 1.9359x; 1.0200x over previous
//
#include <hip/hip_runtime.h>

// Fused 3-level B3-spline UWT via composed dense kernels, fp32.
// x: (16,1024,1024) -> out: (16,4,1024,1024) = [w1,w2,w3,c3].
// c_i = V_i U_i x with composed taps: L1 5-tap, L2 13-tap, L3 29-tap.
// 64x64 output tile, 92x96 input tile, 2 barriers, 78.3 KB LDS -> 2 blocks/CU.
// TB=256: passB threads own 4-row strips (vs 2) halving LDS read/scalar.
// All LDS buffers use f4-granularity XOR swizzle (col4 ^= row&7).

typedef float f4v __attribute__((ext_vector_type(4)));

constexpr int TB   = 256;
constexpr int TROW = 64;
constexpr int TCOL = 64;
constexpr int VH   = 14;          // vertical halo (2+4+8)
constexpr int XR   = TROW + 28;   // 92 x-tile rows
constexpr int XP   = 96;          // x-tile pitch (f4-swizzled, no pad needed)
constexpr int U2R  = TROW + 12;   // 76
constexpr int U3R  = TROW + 28;   // 92
constexpr int UP   = 64;
constexpr int HW   = 1024 * 1024;

__device__ constexpr float K5[5] = {0.0625f, 0.25f, 0.375f, 0.25f, 0.0625f};
__device__ constexpr float K13[13] = {
    1.f/256, 4.f/256, 10.f/256, 20.f/256, 31.f/256, 40.f/256, 44.f/256,
    40.f/256, 31.f/256, 20.f/256, 10.f/256, 4.f/256, 1.f/256};
__device__ constexpr float K29[29] = {
    1.f/4096,   4.f/4096,  10.f/4096,  20.f/4096,  35.f/4096,  56.f/4096,
    84.f/4096, 120.f/4096, 161.f/4096, 204.f/4096, 246.f/4096, 284.f/4096,
    315.f/4096, 336.f/4096, 344.f/4096, 336.f/4096, 315.f/4096, 284.f/4096,
    246.f/4096, 204.f/4096, 161.f/4096, 120.f/4096,  84.f/4096,  56.f/4096,
    35.f/4096,  20.f/4096,  10.f/4096,   4.f/4096,   1.f/4096};

__device__ __forceinline__ int refl(int i) {
    return i < 0 ? -i : (i >= 1024 ? 2046 - i : i);
}
// f4-granular XOR swizzle; bijective for c4 in [0,24) since c4^7 stays in range.
__device__ __forceinline__ int xidx(int r, int c4) { return r * XP + 4 * (c4 ^ (r & 7)); }
__device__ __forceinline__ int uidx(int r, int q)  { return r * UP + 4 * (q  ^ (r & 7)); }

__global__ __launch_bounds__(TB, 2)
void uwt3_kernel(const float* __restrict__ x, float* __restrict__ out)
{
    __shared__ float xs[XR * XP];     // 35.3 KB
    __shared__ float u2s[U2R * UP];   // 19.0 KB
    __shared__ float u3s[U3R * UP];   // 23.0 KB

    const int tid = threadIdx.x;

    // bijective XCD chunk swizzle (4096 % 8 == 0)
    const int flat = blockIdx.x;
    const int swz  = (flat & 7) * 512 + (flat >> 3);
    const int bxi = swz & 15;
    const int byi = (swz >> 4) & 15;
    const int bz  = swz >> 8;
    const int bx = bxi * TCOL;
    const int by = byi * TROW;

    const float* xp = x + (size_t)bz * HW;
    float* op = out + (size_t)bz * 4 * HW;

    // ---- load x tile: rows [by-14, by+78), cols [bx-16, bx+80) ----
    if (bxi != 0 && bxi != 15) {
        for (int e = tid; e < XR * 24; e += TB) {
            const int r = e / 24, m = e - r * 24;
            const int gr = refl(by - VH + r);
            const f4v v = *(const f4v*)(xp + (size_t)gr * 1024 + (bx - 16 + 4 * m));
            *(f4v*)(xs + xidx(r, m)) = v;
        }
    } else {
        for (int e = tid; e < XR * 96; e += TB) {
            const int r = e / 96, c = e - r * 96;
            const int gr = refl(by - VH + r);
            const int gc = refl(bx - 16 + c);
            xs[xidx(r, c >> 2) + (c & 3)] = xp[(size_t)gr * 1024 + gc];
        }
    }
    __syncthreads();

    // ---- passA: horizontal composed convs -> u2 (13-tap), u3 (29-tap) ----
    for (int t = tid; t < XR * 4; t += TB) {
        const int gi = t & 3;          // 16-float output group
        const int rp = t >> 2;         // xs row
        float F[48];
#pragma unroll
        for (int m = 0; m < 12; ++m)
            *(f4v*)&F[4 * m] = *(const f4v*)(xs + xidx(rp, 4 * gi + m));
#pragma unroll
        for (int k = 0; k < 4; ++k) {
            f4v a = {0.f, 0.f, 0.f, 0.f};
#pragma unroll
            for (int tt = 0; tt < 29; ++tt) {
#pragma unroll
                for (int q = 0; q < 4; ++q)
                    a[q] += K29[tt] * F[2 + 4 * k + q + tt];
            }
            *(f4v*)(u3s + uidx(rp, 4 * gi + k)) = a;
        }
        if (rp >= 8 && rp < 8 + U2R) {
#pragma unroll
            for (int k = 0; k < 4; ++k) {
                f4v a = {0.f, 0.f, 0.f, 0.f};
#pragma unroll
                for (int tt = 0; tt < 13; ++tt) {
#pragma unroll
                    for (int q = 0; q < 4; ++q)
                        a[q] += K13[tt] * F[10 + 4 * k + q + tt];
                }
                *(f4v*)(u2s + uidx(rp - 8, 4 * gi + k)) = a;
            }
        }
    }
    __syncthreads();

    // ---- passB: vertical convs + all 4 outputs; thread = (f4-col, 4-row strip) ----
    const int fc = tid & 15;
    const int r0 = (tid >> 4) * 4;
    const size_t gbase = (size_t)(by + r0) * 1024 + bx + 4 * fc;

    // c1 = V1(U1 x) directly from x tile; capture x center for w1
    f4v c1[4], xc[4];
    {
        f4v u1r[8];
#pragma unroll
        for (int i = 0; i < 8; ++i) {
            float f[12];
#pragma unroll
            for (int m = 0; m < 3; ++m)
                *(f4v*)&f[4 * m] = *(const f4v*)(xs + xidx(r0 + 12 + i, fc + 3 + m));
            if (i >= 2 && i < 6) xc[i - 2] = *(const f4v*)&f[4];
            f4v a = {0.f, 0.f, 0.f, 0.f};
#pragma unroll
            for (int t = 0; t < 5; ++t) {
#pragma unroll
                for (int q = 0; q < 4; ++q)
                    a[q] += K5[t] * f[2 + q + t];
            }
            u1r[i] = a;
        }
#pragma unroll
        for (int j = 0; j < 4; ++j) {
            f4v a = {0.f, 0.f, 0.f, 0.f};
#pragma unroll
            for (int t = 0; t < 5; ++t)
                a += K5[t] * u1r[j + t];
            c1[j] = a;
        }
    }
#pragma unroll
    for (int j = 0; j < 4; ++j)
        __builtin_nontemporal_store(xc[j] - c1[j],
            (f4v*)(op + 0 * HW + gbase + (size_t)j * 1024));

    // c2 = V2 u2 (13-tap dense over 16-row window)
    f4v c2[4] = {{0,0,0,0},{0,0,0,0},{0,0,0,0},{0,0,0,0}};
#pragma unroll
    for (int i = 0; i < 16; ++i) {
        const f4v v = *(const f4v*)(u2s + uidx(r0 + i, fc));
#pragma unroll
        for (int j = 0; j < 4; ++j) {
            const int m = i - j;
            if (m >= 0 && m <= 12) c2[j] += K13[m] * v;
        }
    }
#pragma unroll
    for (int j = 0; j < 4; ++j)
        __builtin_nontemporal_store(c1[j] - c2[j],
            (f4v*)(op + 1 * HW + gbase + (size_t)j * 1024));

    // c3 = V3 u3 (29-tap dense over 32-row window)
    f4v c3[4] = {{0,0,0,0},{0,0,0,0},{0,0,0,0},{0,0,0,0}};
#pragma unroll
    for (int i = 0; i < 32; ++i) {
        const f4v v = *(const f4v*)(u3s + uidx(r0 + i, fc));
#pragma unroll
        for (int j = 0; j < 4; ++j) {
            const int m = i - j;
            if (m >= 0 && m <= 28) c3[j] += K29[m] * v;
        }
    }
#pragma unroll
    for (int j = 0; j < 4; ++j) {
        __builtin_nontemporal_store(c2[j] - c3[j],
            (f4v*)(op + 2 * HW + gbase + (size_t)j * 1024));
        __builtin_nontemporal_store(c3[j],
            (f4v*)(op + 3 * HW + gbase + (size_t)j * 1024));
    }
}

extern "C" void kernel_launch(void* const* d_in, const int* in_sizes, int n_in,
                              void* d_out, int out_size, void* d_ws, size_t ws_size,
                              hipStream_t stream)
{
    const float* x = (const float*)d_in[0];
    float* out = (float*)d_out;
    uwt3_kernel<<<dim3(4096), dim3(TB), 0, stream>>>(x, out);
}